// Round 1
// baseline (2982.118 us; speedup 1.0000x reference)
//
#include <hip/hip_runtime.h>

// ---------------------------------------------------------------------------
// GraphSAGE (mean) x2 + linear head, fp32.
// Buffers in d_ws: deg[Npad] | bufA[N*128] (segment sums) | bufB[N*128] (h)
// ---------------------------------------------------------------------------

__global__ void degree_kernel(const int* __restrict__ dst, int E,
                              float* __restrict__ deg) {
    int i = blockIdx.x * blockDim.x + threadIdx.x;
    if (i < E) atomicAdd(&deg[dst[i]], 1.0f);
}

// 32 threads per edge, 4 channels (float4) per thread.
__global__ void scatter_kernel(const float* __restrict__ feat,
                               const int* __restrict__ src,
                               const int* __restrict__ dst, int E,
                               float* __restrict__ sums) {
    int gid = blockIdx.x * blockDim.x + threadIdx.x;
    int e = gid >> 5;
    if (e >= E) return;
    int c4 = (gid & 31) << 2;
    int s = src[e];
    int d = dst[e];
    const float4 v = *(const float4*)(feat + (long long)s * 128 + c4);
    float* p = sums + (long long)d * 128 + c4;
    atomicAdd(p + 0, v.x);
    atomicAdd(p + 1, v.y);
    atomicAdd(p + 2, v.z);
    atomicAdd(p + 3, v.w);
}

// h[i,:] = relu( (sums[i,:]/max(deg[i],1)) @ Wl + bl + xin[i,:] @ Wr )
// Block: 256 threads, 32 rows x 128 cols tile; thread computes 4 rows x 4 cols.
__global__ __launch_bounds__(256) void sage_gemm_kernel(
    const float* __restrict__ xin, const float* __restrict__ sums,
    const float* __restrict__ deg, const float* __restrict__ Wl,
    const float* __restrict__ bl, const float* __restrict__ Wr,
    float* __restrict__ out, int N) {
    __shared__ float aggL[32 * 128];
    __shared__ float xL[32 * 128];
    __shared__ float invL[32];

    const int i0 = blockIdx.x * 32;
    const int t = threadIdx.x;

    if (t < 32) {
        int row = i0 + t;
        float d = (row < N) ? deg[row] : 1.0f;
        invL[t] = 1.0f / fmaxf(d, 1.0f);
    }
    __syncthreads();

    // Stage 32x128 tiles of mean-agg and root features (float4 per thread x4).
    for (int f4 = t; f4 < 1024; f4 += 256) {
        int row = f4 >> 5;
        int c4 = (f4 & 31) << 2;
        int gr = i0 + row;
        float4 a = make_float4(0.f, 0.f, 0.f, 0.f);
        float4 xv = make_float4(0.f, 0.f, 0.f, 0.f);
        if (gr < N) {
            a = *(const float4*)(sums + (long long)gr * 128 + c4);
            xv = *(const float4*)(xin + (long long)gr * 128 + c4);
        }
        float inv = invL[row];
        a.x *= inv; a.y *= inv; a.z *= inv; a.w *= inv;
        *(float4*)(aggL + row * 128 + c4) = a;
        *(float4*)(xL + row * 128 + c4) = xv;
    }
    __syncthreads();

    const int rr = t >> 5;          // 0..7  (row group of 4)
    const int c0 = (t & 31) << 2;   // 0..124 (col group of 4)

    float acc[4][4] = {};
#pragma unroll 4
    for (int k = 0; k < 128; ++k) {
        float4 wl = *(const float4*)(Wl + k * 128 + c0);
        float4 wr = *(const float4*)(Wr + k * 128 + c0);
#pragma unroll
        for (int r = 0; r < 4; ++r) {
            float a = aggL[(rr * 4 + r) * 128 + k];
            float xv = xL[(rr * 4 + r) * 128 + k];
            acc[r][0] += a * wl.x + xv * wr.x;
            acc[r][1] += a * wl.y + xv * wr.y;
            acc[r][2] += a * wl.z + xv * wr.z;
            acc[r][3] += a * wl.w + xv * wr.w;
        }
    }

    const float4 bias = *(const float4*)(bl + c0);
#pragma unroll
    for (int r = 0; r < 4; ++r) {
        int row = i0 + rr * 4 + r;
        if (row < N) {
            float4 o;
            o.x = fmaxf(acc[r][0] + bias.x, 0.f);
            o.y = fmaxf(acc[r][1] + bias.y, 0.f);
            o.z = fmaxf(acc[r][2] + bias.z, 0.f);
            o.w = fmaxf(acc[r][3] + bias.w, 0.f);
            *(float4*)(out + (long long)row * 128 + c0) = o;
        }
    }
}

// out[i] = dot(h[i,:], Wout) + bout   (one wave per row)
__global__ void head_kernel(const float* __restrict__ h,
                            const float* __restrict__ Wout,
                            const float* __restrict__ bout,
                            float* __restrict__ out, int N) {
    int i = blockIdx.x * 4 + (threadIdx.x >> 6);
    int lane = threadIdx.x & 63;
    if (i >= N) return;
    const float* hp = h + (long long)i * 128;
    float s = hp[lane] * Wout[lane] + hp[lane + 64] * Wout[lane + 64];
#pragma unroll
    for (int off = 32; off > 0; off >>= 1) s += __shfl_down(s, off);
    if (lane == 0) out[i] = s + bout[0];
}

extern "C" void kernel_launch(void* const* d_in, const int* in_sizes, int n_in,
                              void* d_out, int out_size, void* d_ws,
                              size_t ws_size, hipStream_t stream) {
    const float* x = (const float*)d_in[0];
    const int* ei = (const int*)d_in[1];
    const float* W1l = (const float*)d_in[2];
    const float* b1l = (const float*)d_in[3];
    const float* W1r = (const float*)d_in[4];
    const float* W2l = (const float*)d_in[5];
    const float* b2l = (const float*)d_in[6];
    const float* W2r = (const float*)d_in[7];
    const float* Wout = (const float*)d_in[8];
    const float* bout = (const float*)d_in[9];

    const int N = in_sizes[0] / 128;
    const int E = in_sizes[1] / 2;
    const int* src = ei;
    const int* dst = ei + E;

    float* deg = (float*)d_ws;
    const size_t Npad = (size_t)((N + 63) & ~63);
    float* bufA = deg + Npad;                 // segment sums
    float* bufB = bufA + (size_t)N * 128;     // hidden activations
    float* out = (float*)d_out;

    // Zero deg + bufA in one memset (contiguous).
    hipMemsetAsync(d_ws, 0, (Npad + (size_t)N * 128) * sizeof(float), stream);

    degree_kernel<<<(E + 255) / 256, 256, 0, stream>>>(dst, E, deg);

    // ---- Layer 1 ----
    {
        int total = E * 32;
        scatter_kernel<<<(total + 255) / 256, 256, 0, stream>>>(x, src, dst, E,
                                                                bufA);
        sage_gemm_kernel<<<(N + 31) / 32, 256, 0, stream>>>(x, bufA, deg, W1l,
                                                            b1l, W1r, bufB, N);
    }

    // ---- Layer 2 ----
    hipMemsetAsync(bufA, 0, (size_t)N * 128 * sizeof(float), stream);
    {
        int total = E * 32;
        scatter_kernel<<<(total + 255) / 256, 256, 0, stream>>>(bufB, src, dst,
                                                                E, bufA);
        sage_gemm_kernel<<<(N + 31) / 32, 256, 0, stream>>>(bufB, bufA, deg,
                                                            W2l, b2l, W2r,
                                                            bufB, N);
    }

    // ---- Head ----
    head_kernel<<<(N + 3) / 4, 256, 0, stream>>>(bufB, Wout, bout, out, N);
}

// Round 2
// 649.036 us; speedup vs baseline: 4.5947x; 4.5947x over previous
//
#include <hip/hip_runtime.h>

#define D 128

// ---------------------------------------------------------------------------
// GraphSAGE (mean) x2 + head, fp32.  CSR-by-dst built per call, then
// gather-based aggregation fused into each layer's GEMM.
// d_ws layout (ints): cnt[Npad] | cursor[Npad] | row_ofs[Npad] | csr[Epad]
//                     | h (float, N*128)
// ---------------------------------------------------------------------------

__global__ void hist_kernel(const int* __restrict__ dst, int E,
                            int* __restrict__ cnt) {
    int i = blockIdx.x * blockDim.x + threadIdx.x;
    if (i < E) atomicAdd(&cnt[dst[i]], 1);
}

// Single-block exclusive scan over N counts -> row_ofs[0..N], cursor copy.
__global__ __launch_bounds__(1024) void scan_kernel(
    const int* __restrict__ cnt, int* __restrict__ row_ofs,
    int* __restrict__ cursor, int N) {
    __shared__ int part[1024];
    const int t = threadIdx.x;
    const int chunk = (N + 1023) >> 10;
    const int lo = t * chunk;
    const int hi = min(lo + chunk, N);
    int s = 0;
    for (int i = lo; i < hi; ++i) s += cnt[i];
    part[t] = s;
    __syncthreads();
    for (int off = 1; off < 1024; off <<= 1) {
        int old_t = part[t];
        int u = (t >= off) ? part[t - off] : 0;
        __syncthreads();
        part[t] = old_t + u;
        __syncthreads();
    }
    int excl = (t == 0) ? 0 : part[t - 1];
    for (int i = lo; i < hi; ++i) {
        int c = cnt[i];
        row_ofs[i] = excl;
        cursor[i] = excl;
        excl += c;
    }
    if (t == 1023) row_ofs[N] = excl;
}

__global__ void fill_kernel(const int* __restrict__ src,
                            const int* __restrict__ dst, int E,
                            int* __restrict__ cursor, int* __restrict__ csr) {
    int e = blockIdx.x * blockDim.x + threadIdx.x;
    if (e < E) {
        int p = atomicAdd(&cursor[dst[e]], 1);
        csr[p] = src[e];
    }
}

// Fused: mean-aggregate 32 rows into LDS (gather via CSR), stage root rows,
// then dual GEMM (+bias, relu). HEAD=true additionally folds the final
// Linear(128,1) and writes one scalar per row.
template <bool HEAD>
__global__ __launch_bounds__(256) void sage_kernel(
    const float* __restrict__ xin, const int* __restrict__ csr,
    const int* __restrict__ row_ofs, const float* __restrict__ Wl,
    const float* __restrict__ bl, const float* __restrict__ Wr,
    const float* __restrict__ Wout, const float* __restrict__ bout,
    float* __restrict__ out, int N) {
    __shared__ float aggL[32 * D];
    __shared__ float xL[32 * D];

    const int i0 = blockIdx.x * 32;
    const int t = threadIdx.x;
    const int g = t >> 5;        // group 0..7, handles rows g*4..g*4+3
    const int l = t & 31;
    const int c4 = l << 2;       // this lane's 4 channels

    // ---- aggregation phase: gather + mean into LDS ----
    for (int sub = 0; sub < 4; ++sub) {
        const int r = g * 4 + sub;
        const int gr = i0 + r;
        float4 acc = make_float4(0.f, 0.f, 0.f, 0.f);
        float4 xv = make_float4(0.f, 0.f, 0.f, 0.f);
        if (gr < N) {
            const int rs = row_ofs[gr];
            const int re = row_ofs[gr + 1];
            for (int e = rs; e < re; ++e) {
                const int s = csr[e];
                const float4 v = *(const float4*)(xin + (long long)s * D + c4);
                acc.x += v.x; acc.y += v.y; acc.z += v.z; acc.w += v.w;
            }
            const float inv = 1.0f / fmaxf((float)(re - rs), 1.0f);
            acc.x *= inv; acc.y *= inv; acc.z *= inv; acc.w *= inv;
            xv = *(const float4*)(xin + (long long)gr * D + c4);
        }
        *(float4*)(aggL + r * D + c4) = acc;
        *(float4*)(xL + r * D + c4) = xv;
    }
    __syncthreads();

    // ---- GEMM phase: 4 rows x 4 cols per thread ----
    float acc[4][4] = {};
#pragma unroll 4
    for (int k = 0; k < D; ++k) {
        float4 wl = *(const float4*)(Wl + k * D + c4);
        float4 wr = *(const float4*)(Wr + k * D + c4);
#pragma unroll
        for (int r = 0; r < 4; ++r) {
            float a = aggL[(g * 4 + r) * D + k];
            float xv = xL[(g * 4 + r) * D + k];
            acc[r][0] += a * wl.x + xv * wr.x;
            acc[r][1] += a * wl.y + xv * wr.y;
            acc[r][2] += a * wl.z + xv * wr.z;
            acc[r][3] += a * wl.w + xv * wr.w;
        }
    }

    const float4 bias = *(const float4*)(bl + c4);
    if (!HEAD) {
#pragma unroll
        for (int r = 0; r < 4; ++r) {
            int row = i0 + g * 4 + r;
            if (row < N) {
                float4 o;
                o.x = fmaxf(acc[r][0] + bias.x, 0.f);
                o.y = fmaxf(acc[r][1] + bias.y, 0.f);
                o.z = fmaxf(acc[r][2] + bias.z, 0.f);
                o.w = fmaxf(acc[r][3] + bias.w, 0.f);
                *(float4*)(out + (long long)row * D + c4) = o;
            }
        }
    } else {
        const float4 wo = *(const float4*)(Wout + c4);
        const float b0 = bout[0];
#pragma unroll
        for (int r = 0; r < 4; ++r) {
            float hx = fmaxf(acc[r][0] + bias.x, 0.f);
            float hy = fmaxf(acc[r][1] + bias.y, 0.f);
            float hz = fmaxf(acc[r][2] + bias.z, 0.f);
            float hw = fmaxf(acc[r][3] + bias.w, 0.f);
            float p = hx * wo.x + hy * wo.y + hz * wo.z + hw * wo.w;
            // reduce across the 32 lanes of this group (32-aligned in wave)
            p += __shfl_xor(p, 16);
            p += __shfl_xor(p, 8);
            p += __shfl_xor(p, 4);
            p += __shfl_xor(p, 2);
            p += __shfl_xor(p, 1);
            int row = i0 + g * 4 + r;
            if (l == 0 && row < N) out[row] = p + b0;
        }
    }
}

extern "C" void kernel_launch(void* const* d_in, const int* in_sizes, int n_in,
                              void* d_out, int out_size, void* d_ws,
                              size_t ws_size, hipStream_t stream) {
    const float* x = (const float*)d_in[0];
    const int* ei = (const int*)d_in[1];
    const float* W1l = (const float*)d_in[2];
    const float* b1l = (const float*)d_in[3];
    const float* W1r = (const float*)d_in[4];
    const float* W2l = (const float*)d_in[5];
    const float* b2l = (const float*)d_in[6];
    const float* W2r = (const float*)d_in[7];
    const float* Wout = (const float*)d_in[8];
    const float* bout = (const float*)d_in[9];

    const int N = in_sizes[0] / D;
    const int E = in_sizes[1] / 2;
    const int* src = ei;
    const int* dst = ei + E;

    const size_t Npad = (size_t)((N + 2 + 255) & ~255);
    const size_t Epad = (size_t)((E + 255) & ~255);
    int* cnt = (int*)d_ws;
    int* cursor = cnt + Npad;
    int* row_ofs = cursor + Npad;
    int* csr = row_ofs + Npad;
    float* h = (float*)(csr + Epad);
    float* out = (float*)d_out;

    // ---- CSR build ----
    hipMemsetAsync(cnt, 0, Npad * sizeof(int), stream);
    hist_kernel<<<(E + 255) / 256, 256, 0, stream>>>(dst, E, cnt);
    scan_kernel<<<1, 1024, 0, stream>>>(cnt, row_ofs, cursor, N);
    fill_kernel<<<(E + 255) / 256, 256, 0, stream>>>(src, dst, E, cursor, csr);

    const int nblk = (N + 31) / 32;
    // ---- Layer 1: x -> h ----
    sage_kernel<false><<<nblk, 256, 0, stream>>>(x, csr, row_ofs, W1l, b1l,
                                                 W1r, nullptr, nullptr, h, N);
    // ---- Layer 2 + head: h -> out ----
    sage_kernel<true><<<nblk, 256, 0, stream>>>(h, csr, row_ofs, W2l, b2l, W2r,
                                                Wout, bout, out, N);
}